// Round 1
// baseline (145.018 us; speedup 1.0000x reference)
//
#include <hip/hip_runtime.h>

// Capsule routing layer, MI355X.
// B=2048, I=64 (in caps), O=32 (out caps), DI=DO=16, 3 routing iters.
// Block = 256 threads (4 waves), handles one o and NB=16 b's.
// A-phase: lane=i, wave w owns d in [4w,4w+4); W+noise in regs (64 VGPR/lane).
// B-phase: lane=(bb,d); priors[i=0..63] in regs; softmax serial per lane.

#define NB 16
#define THREADS 256

__global__ __launch_bounds__(THREADS) void routing_kernel(
    const float* __restrict__ x,    // (B, DI, I)  = (2048,16,64)
    const float* __restrict__ rw,   // (O, I, DO, DI) = (32,64,16,16)
    const float* __restrict__ ns,   // same as rw
    float* __restrict__ out)        // (1, O, B, DO)
{
    extern __shared__ float p_lds[]; // 16384 floats = 64 KB, [row=bb*16+d][64 i, swizzled]

    const int tid  = threadIdx.x;
    const int w    = tid >> 6;      // wave id 0..3
    const int lane = tid & 63;

    const int o  = blockIdx.x & 31;
    const int bc = blockIdx.x >> 5; // b chunk 0..127

    // ---- load W+noise fragment into registers: lane=i, d = 4w+dp ----
    float wq[4][4][4]; // [dp][eq][k]  -> W[o, lane, 4w+dp, 4eq+k]
    {
        const int base = (o * 64 + lane) * 256 + (w * 4) * 16;
        #pragma unroll
        for (int dp = 0; dp < 4; ++dp) {
            #pragma unroll
            for (int eq = 0; eq < 4; ++eq) {
                const int idx = base + dp * 16 + eq * 4;
                const float4 a = *reinterpret_cast<const float4*>(rw + idx);
                const float4 n = *reinterpret_cast<const float4*>(ns + idx);
                wq[dp][eq][0] = a.x + n.x;
                wq[dp][eq][1] = a.y + n.y;
                wq[dp][eq][2] = a.z + n.z;
                wq[dp][eq][3] = a.w + n.w;
            }
        }
    }

    // ---- A phase: priors -> LDS ----
    for (int bb = 0; bb < NB; ++bb) {
        const int b = bc * NB + bb;
        const float* xb = x + b * 1024 + lane;
        float xv[16];
        #pragma unroll
        for (int e = 0; e < 16; ++e) xv[e] = xb[e * 64];

        #pragma unroll
        for (int dp = 0; dp < 4; ++dp) {
            float acc = 0.f;
            #pragma unroll
            for (int eq = 0; eq < 4; ++eq) {
                acc = fmaf(wq[dp][eq][0], xv[4*eq+0], acc);
                acc = fmaf(wq[dp][eq][1], xv[4*eq+1], acc);
                acc = fmaf(wq[dp][eq][2], xv[4*eq+2], acc);
                acc = fmaf(wq[dp][eq][3], xv[4*eq+3], acc);
            }
            const int d   = w * 4 + dp;
            const int row = bb * 16 + d;
            // XOR-swizzle the 16B slot by (d&7) so B-phase b128 reads are spread
            const int fi = row * 64 + ((((lane >> 2) ^ (d & 7)) << 2) | (lane & 3));
            p_lds[fi] = acc;
        }
    }

    __syncthreads();

    // ---- B phase: routing. lane = bb*16 + d; wave handles 4 (b,o) pairs ----
    {
        const int bb = lane >> 4;   // 0..3
        const int d  = lane & 15;
        const int bp = w * 4 + bb;  // b within chunk
        const int row = bp * 16 + d;

        const float4* pl = reinterpret_cast<const float4*>(p_lds) + row * 16;
        float p[64];
        #pragma unroll
        for (int g = 0; g < 16; ++g) {
            const float4 v = pl[g ^ (d & 7)];
            p[4*g+0] = v.x; p[4*g+1] = v.y; p[4*g+2] = v.z; p[4*g+3] = v.w;
        }

        // ---- iter 1: softmax(0) = uniform 1/64 ----
        float ssum = 0.f;
        #pragma unroll
        for (int i = 0; i < 64; ++i) ssum += p[i];
        float s = ssum * (1.0f / 64.0f);

        float sn = s * s;                 // squash norm over d (16-lane group)
        sn += __shfl_xor(sn, 1);
        sn += __shfl_xor(sn, 2);
        sn += __shfl_xor(sn, 4);
        sn += __shfl_xor(sn, 8);
        float factor = sqrtf(sn) / (1.0f + sn);
        float Vsum = s * factor;          // logits[i,d] = p[i,d] * Vsum[d]

        float pmax = p[0], pmin = p[0];
        #pragma unroll
        for (int i = 1; i < 64; ++i) { pmax = fmaxf(pmax, p[i]); pmin = fminf(pmin, p[i]); }

        // ---- iters 2,3 ----
        #pragma unroll
        for (int it = 0; it < 2; ++it) {
            const float c = Vsum * 1.44269504089f;      // log2(e) folded
            const float M = (c >= 0.f ? pmax : pmin) * c; // max logit (log2 units)
            float denom = 0.f, num = 0.f;
            #pragma unroll
            for (int i = 0; i < 64; ++i) {
                const float E = exp2f(fmaf(p[i], c, -M));
                denom += E;
                num = fmaf(E, p[i], num);
            }
            s = num / denom;
            sn = s * s;
            sn += __shfl_xor(sn, 1);
            sn += __shfl_xor(sn, 2);
            sn += __shfl_xor(sn, 4);
            sn += __shfl_xor(sn, 8);
            factor = sqrtf(sn) / (1.0f + sn);
            Vsum += s * factor;
        }

        const int b = bc * NB + bp;
        out[(o * 2048 + b) * 16 + d] = s * factor;  // (1,O,B,DO)
    }
}

extern "C" void kernel_launch(void* const* d_in, const int* in_sizes, int n_in,
                              void* d_out, int out_size, void* d_ws, size_t ws_size,
                              hipStream_t stream) {
    const float* x  = (const float*)d_in[0];
    const float* rw = (const float*)d_in[1];
    const float* ns = (const float*)d_in[2];
    float* out = (float*)d_out;
    (void)d_ws; (void)ws_size; (void)in_sizes; (void)n_in; (void)out_size;

    const int grid = (2048 / NB) * 32; // 4096 blocks: blockIdx = bc*32 + o
    routing_kernel<<<grid, THREADS, 65536, stream>>>(x, rw, ns, out);
}